// Round 3
// baseline (256.864 us; speedup 1.0000x reference)
//
#include <hip/hip_runtime.h>

#define NN     50000
#define E_RAW  800000
#define ETOT   (E_RAW + NN)   /* 850000: edges + self loops */
#define FIN    128
#define FH     256            /* HEADS*HID */
#define NEG    0.2f
#define BCAP   64             /* bucket capacity; P(deg>64) ~ 1e-18 */
#define L2E    1.44269504f    /* log2(e) */

/* Counting-sort CSR build.  R9: global atomics cap ~11 ops/ns -> LDS
   histograms.  R14 lesson: scatter needs its own 1024-thr dispatch.
   R15: P_PART 16->8 halves redundant edge-stream scanning. */
#define P_PART 8
#define DPW    6250             /* dsts per partition, 25KB LDS */
#define R_REP  32
#define EPW    (E_RAW / R_REP)  /* 25000 edges per replica */
#define CNT_WGS (P_PART * R_REP) /* 256 */
#define PREP_WGS 8              /* W1 transpose: 8 x 4096 elems */
#define OFF_NB  ((NN + 255) / 256)   /* 196 offset blocks */
#define GEMM_NB ((NN + 63) / 64)     /* 782 gemm blocks */
#define AGG1_WORK 25000         /* (NN/4 groups) x 2 channel halves */
#define AGG1_GRID 2048          /* persistent: 8 blocks/CU, stride%8==0 */

typedef __attribute__((ext_vector_type(8))) short s16x8;
typedef __attribute__((ext_vector_type(4))) float f32x4;

static __device__ __forceinline__ float leaky(float v) { return fmaxf(v, NEG * v); }

// 2^x via v_exp_f32 (exactly what __expf lowers to, minus the log2e mul)
static __device__ __forceinline__ float ex2(float x) {
    float r; asm("v_exp_f32 %0, %1" : "=v"(r) : "v"(x)); return r;
}

// RNE float->bf16
static __device__ __forceinline__ unsigned short f2bf(float f) {
    unsigned u = __float_as_uint(f);
    unsigned r = u + 0x7fffu + ((u >> 16) & 1u);
    return (unsigned short)(r >> 16);
}

// ---------------------------------------------------------------------------
// D1: count pass + W1 prep.
// ---------------------------------------------------------------------------
__global__ __launch_bounds__(1024) void k_count(const int* __restrict__ ei,
                                                const float* __restrict__ W1,
                                                unsigned short* __restrict__ Wt_bf,
                                                int* __restrict__ pcnt)
{
    const int t = threadIdx.x;
    if (blockIdx.x >= CNT_WGS) {
        const int base = (blockIdx.x - CNT_WGS) * 4096;
        for (int i = t; i < 4096; i += 1024) {
            int idx = base + i;                 // < 32768
            int k = idx >> 8, col = idx & 255;
            Wt_bf[col * FIN + k] = f2bf(W1[k * FH + col]);
        }
        return;
    }
    __shared__ int lcnt[DPW];
    const int p  = blockIdx.x >> 5;
    const int r  = blockIdx.x & 31;
    const int lo = p * DPW;
    for (int i = t; i < DPW; i += 1024) lcnt[i] = 0;
    __syncthreads();
    const int ebase = r * EPW, eend = ebase + EPW;
    for (int e0 = ebase + t * 4; e0 < eend; e0 += 4096) {
        int4 dv4 = *(const int4*)&ei[E_RAW + e0];   // coalesced 16B
#pragma unroll
        for (int k = 0; k < 4; k++) {
            unsigned rel = (unsigned)((&dv4.x)[k] - lo);
            if (rel < DPW) atomicAdd(&lcnt[rel], 1);   // LDS, no return
        }
    }
    __syncthreads();
    for (int i = t; i < DPW; i += 1024)
        pcnt[r * NN + lo + i] = lcnt[i];
}

// ---------------------------------------------------------------------------
// D2: FUSED offsets + gemm.  a_s/a_d stores pre-scaled by log2(e) (leaky
// commutes with positive scale) so k_agg1 uses raw v_exp_f32.
// ---------------------------------------------------------------------------
__global__ __launch_bounds__(256) void k_gx(const float* __restrict__ x,
                                            const unsigned short* __restrict__ Wt_bf,
                                            const float* __restrict__ att_src,
                                            const float* __restrict__ att_dst,
                                            const int* __restrict__ pcnt,
                                            int* __restrict__ soff,
                                            int* __restrict__ cnt,
                                            unsigned short* __restrict__ csr16,
                                            unsigned short* __restrict__ h1b,
                                            float* __restrict__ a_s,
                                            float* __restrict__ a_d)
{
    const int t = threadIdx.x;
    if (blockIdx.x < OFF_NB) {
        int d = blockIdx.x * 256 + t;
        if (d >= NN) return;
        int run = 1;                     // slot 0 = self loop
#pragma unroll
        for (int r = 0; r < R_REP; r++) {
            soff[r * NN + d] = run;
            run += pcnt[r * NN + d];
        }
        cnt[d] = run;                    // clamped at use
        csr16[(size_t)d << 6] = (unsigned short)d;   // self-loop src
        return;
    }

    // ---------------- gemm path ----------------
    __shared__ unsigned short Sbuf[64 * 256];
    const int w    = t >> 6;
    const int lane = t & 63;
    const int li   = lane & 15;
    const int q8   = (lane >> 4) * 8;
    const int quad = lane >> 4;
    const int n0   = (blockIdx.x - OFF_NB) * 64;

    {
        const int node_l = t >> 2;
        const int k0 = (t & 3) * 32;
        int nn = n0 + node_l; if (nn >= NN) nn = NN - 1;
        const float* xp = &x[(size_t)nn * FIN + k0];
        unsigned short* xd = &Sbuf[node_l * 136 + k0];
#pragma unroll
        for (int i = 0; i < 8; i++) {
            float4 v = *(const float4*)&xp[i * 4];
            xd[i * 4 + 0] = f2bf(v.x);
            xd[i * 4 + 1] = f2bf(v.y);
            xd[i * 4 + 2] = f2bf(v.z);
            xd[i * 4 + 3] = f2bf(v.w);
        }
    }
    __syncthreads();

    f32x4 acc[4][4];
#pragma unroll
    for (int i = 0; i < 4; i++)
#pragma unroll
        for (int j = 0; j < 4; j++) acc[i][j] = (f32x4){0.f, 0.f, 0.f, 0.f};

#pragma unroll
    for (int kki = 0; kki < 4; kki++) {
        const int kk = kki * 32;
        s16x8 af[4], bf[4];
#pragma unroll
        for (int n16 = 0; n16 < 4; n16++) {
            int col = w * 64 + n16 * 16 + li;
            bf[n16] = *(const s16x8*)&Wt_bf[col * FIN + kk + q8];
        }
#pragma unroll
        for (int m16 = 0; m16 < 4; m16++)
            af[m16] = *(const s16x8*)&Sbuf[(m16 * 16 + li) * 136 + kk + q8];
#pragma unroll
        for (int m16 = 0; m16 < 4; m16++)
#pragma unroll
            for (int n16 = 0; n16 < 4; n16++)
                acc[m16][n16] = __builtin_amdgcn_mfma_f32_16x16x32_bf16(
                    af[m16], bf[n16], acc[m16][n16], 0, 0, 0);
    }

    // epilogue A: per-head attention logits (stored pre-scaled by log2 e)
    {
        float as_c[4], ad_c[4];
#pragma unroll
        for (int n16 = 0; n16 < 4; n16++) {
            int col = w * 64 + n16 * 16 + li;
            as_c[n16] = att_src[col];
            ad_c[n16] = att_dst[col];
        }
#pragma unroll
        for (int m16 = 0; m16 < 4; m16++) {
            float ps[4], pd[4];
#pragma unroll
            for (int reg = 0; reg < 4; reg++) {
                float s = 0.f, d = 0.f;
#pragma unroll
                for (int n16 = 0; n16 < 4; n16++) {
                    s += acc[m16][n16][reg] * as_c[n16];
                    d += acc[m16][n16][reg] * ad_c[n16];
                }
                ps[reg] = s; pd[reg] = d;
            }
#pragma unroll
            for (int off = 1; off < 16; off <<= 1) {
#pragma unroll
                for (int reg = 0; reg < 4; reg++) {
                    ps[reg] += __shfl_xor(ps[reg], off);
                    pd[reg] += __shfl_xor(pd[reg], off);
                }
            }
            if (li == 0) {
#pragma unroll
                for (int reg = 0; reg < 4; reg++) {
                    int node = n0 + m16 * 16 + quad * 4 + reg;
                    if (node < NN) {
                        a_s[node * 4 + w] = ps[reg] * L2E;
                        a_d[node * 4 + w] = pd[reg] * L2E;
                    }
                }
            }
        }
    }

    // epilogue B: bf16 store via LDS round-trip
    __syncthreads();
#pragma unroll
    for (int m16 = 0; m16 < 4; m16++)
#pragma unroll
        for (int n16 = 0; n16 < 4; n16++)
#pragma unroll
            for (int reg = 0; reg < 4; reg++)
                Sbuf[(m16 * 16 + quad * 4 + reg) * FH + w * 64 + n16 * 16 + li] =
                    f2bf(acc[m16][n16][reg]);
    __syncthreads();
    {
        const int node_l = t >> 2;
        const int c0 = (t & 3) * 64;
        int node = n0 + node_l;
        if (node < NN) {
#pragma unroll
            for (int i = 0; i < 8; i++)
                *(uint4*)&h1b[(size_t)node * FH + c0 + i * 8] =
                    *(const uint4*)&Sbuf[node_l * FH + c0 + i * 8];
        }
    }
}

// ---------------------------------------------------------------------------
// D3: scatter into contiguous buckets (now uint16 payload: src < 50000 <
// 2^16, halves random write-allocate traffic).  1024-thread WGs.
// ---------------------------------------------------------------------------
__global__ __launch_bounds__(1024) void k_scat2(const int* __restrict__ ei,
                                                const int* __restrict__ soff,
                                                unsigned short* __restrict__ csr16)
{
    __shared__ int cur[DPW];
    const int t  = threadIdx.x;
    const int p  = blockIdx.x >> 5;
    const int r  = blockIdx.x & 31;
    const int lo = p * DPW;
    for (int i = t; i < DPW; i += 1024)
        cur[i] = soff[r * NN + lo + i];
    __syncthreads();
    const int ebase = r * EPW, eend = ebase + EPW;
    for (int e0 = ebase + t * 4; e0 < eend; e0 += 4096) {
        int4 sv4 = *(const int4*)&ei[e0];           // coalesced 16B (src)
        int4 dv4 = *(const int4*)&ei[E_RAW + e0];   // coalesced 16B (dst)
#pragma unroll
        for (int k = 0; k < 4; k++) {
            int d = (&dv4.x)[k];
            unsigned rel = (unsigned)(d - lo);
            if (rel < DPW) {
                int pos = atomicAdd(&cur[rel], 1);  // LDS ds_add_rtn
                if (pos < BCAP)
                    csr16[((size_t)d << 6) + pos] = (unsigned short)(&sv4.x)[k];
            }
        }
    }
}

// ---------------------------------------------------------------------------
// D4: layer-1 aggregation, v4 (R18).  R17 post-mortem: rate DROPPED to 2.6
// TB/s with 4-region-per-instruction loads; v1's one-row-per-instruction ran
// 3.1.  v4 = v1 coalescing x channel split x exact pinning:
//   - one wave per (dst, half); 64 lanes x 2ch -> ONE coalesced 256B dword
//     load per edge-half (single region per instruction).
//   - bucket preloaded once (64 x u16 = 128B); per-edge s via shfl +
//     readfirstlane -> SGPR -> scalar base addressing (zero per-edge VALU
//     address math; a_s1 and h1b loads use sbase + preloaded voffset).
//   - PERSISTENT grid of 2048 blocks (8/CU, all resident, stride%8==0):
//     work%8 == blockIdx%8 forever -> half<->XCD pinning exact, no drift.
//   - exp = raw v_exp_f32 (logits pre-scaled by log2 e in k_gx).
// Epilogue per (dst,half): /z, +b1, ELU, W2 partial -> float2; k_agg2
// recombines.
// ---------------------------------------------------------------------------
__global__ __launch_bounds__(256) void k_agg1(const int* __restrict__ cnt,
                                              const unsigned short* __restrict__ csr16,
                                              const float* __restrict__ a_s1,
                                              const float* __restrict__ a_d1,
                                              const unsigned short* __restrict__ h1b,
                                              const float* __restrict__ b1,
                                              const float* __restrict__ W2,
                                              float2* __restrict__ ndp)
{
    const int t    = threadIdx.x;
    const int lane = t & 63;
    const int wv   = t >> 6;

    for (int wk = blockIdx.x; wk < AGG1_WORK; wk += AGG1_GRID) {
        const int r8   = wk & 7;
        const int half = r8 >> 2;                 // XCDs 0-3: half 0; 4-7: half 1
        const int g    = (wk >> 3) * 4 + (r8 & 3);
        const int n    = g * 4 + wv;              // always < NN

        int m = cnt[n]; if (m > BCAP) m = BCAP;
        const int c0 = half * 128 + lane * 2;     // 2 channels per lane
        const int h  = half * 2 + (lane >> 5);    // head for this lane
        const float ad_h = a_d1[n * 4 + h];
        const unsigned short* sp = &csr16[(size_t)n << 6];
        int sv = sp[lane];                        // whole bucket, 128B coalesced

        const unsigned short* hb = h1b + c0;      // per-lane channel base
        const float* asb = a_s1 + h;              // per-lane head base

        float a0 = 0.f, a1 = 0.f, z = 0.f;
#pragma unroll 4
        for (int j = 0; j < m; ++j) {
            int s = __builtin_amdgcn_readfirstlane(__shfl(sv, j));  // SGPR
            float lg = asb[s * 4] + ad_h;         // sbase(s*16) + voff(h*4)
            float ex = ex2(leaky(lg));            // logits pre-scaled by L2E
            unsigned wd = *(const unsigned*)(hb + (size_t)s * FH);  // 256B/wave
            a0 += __uint_as_float(wd << 16)         * ex;
            a1 += __uint_as_float(wd & 0xffff0000u) * ex;
            z  += ex;
        }

        // epilogue: /z, +b1, ELU, W2 partial projection (2 ch per lane)
        const float rz = 1.0f / z;                // z uniform within 32-lane half
        float2 bb = *(const float2*)&b1[c0];
        float v0 = a0 * rz + bb.x;
        float v1 = a1 * rz + bb.y;
        v0 = v0 > 0.f ? v0 : __expf(v0) - 1.f;    // ELU
        v1 = v1 > 0.f ? v1 : __expf(v1) - 1.f;
        float4 wa = *(const float4*)&W2[c0 * 2];
        float s0 = v0 * wa.x + v1 * wa.z;
        float s1 = v0 * wa.y + v1 * wa.w;
#pragma unroll
        for (int off = 1; off < 64; off <<= 1) {
            s0 += __shfl_xor(s0, off);
            s1 += __shfl_xor(s1, off);
        }
        if (lane == 0)
            ndp[(size_t)half * NN + n] = make_float2(s0, s1);
    }
}

// ---------------------------------------------------------------------------
// D5: layer-2 aggregation, 16 lanes per dst; combines the two channel-half
// partials on the fly (tables 400KB each, L2-resident).  att2/logits folded
// by log2 e -> raw v_exp_f32.
// ---------------------------------------------------------------------------
__global__ __launch_bounds__(256) void k_agg2(const int* __restrict__ cnt,
                                              const unsigned short* __restrict__ csr16,
                                              const float2* __restrict__ ndp,
                                              const float* __restrict__ att_src2,
                                              const float* __restrict__ att_dst2,
                                              const float* __restrict__ b2,
                                              float* __restrict__ out)
{
    const int l = threadIdx.x & 15;
    const int n = blockIdx.x * 16 + (threadIdx.x >> 4);
    if (n >= NN) return;
    int m = cnt[n]; if (m > BCAP) m = BCAP;
    const unsigned short* sp = &csr16[(size_t)n << 6];
    const float as0 = att_src2[0] * L2E, as1 = att_src2[1] * L2E;
    float2 o0 = ndp[n], o1 = ndp[NN + n];
    const float ad = ((o0.x + o1.x) * att_dst2[0] +
                      (o0.y + o1.y) * att_dst2[1]) * L2E;
    float z = 0.f, a0 = 0.f, a1 = 0.f;
    for (int j = l; j < m; j += 16) {
        int s = sp[j];
        float2 f0 = ndp[s], f1 = ndp[NN + s];
        float sx = f0.x + f1.x, sy = f0.y + f1.y;
        float lg = sx * as0 + sy * as1 + ad;
        float ex = ex2(leaky(lg));
        z  += ex;
        a0 += sx * ex;
        a1 += sy * ex;
    }
#pragma unroll
    for (int off = 8; off; off >>= 1) {
        z  += __shfl_xor(z, off);
        a0 += __shfl_xor(a0, off);
        a1 += __shfl_xor(a1, off);
    }
    if (l == 0) {
        out[n * 2 + 0] = a0 / z + b2[0];
        out[n * 2 + 1] = a1 / z + b2[1];
    }
}

extern "C" void kernel_launch(void* const* d_in, const int* in_sizes, int n_in,
                              void* d_out, int out_size, void* d_ws, size_t ws_size,
                              hipStream_t stream)
{
    const float* x        = (const float*)d_in[0];
    const int*   ei       = (const int*)d_in[1];
    const float* W1       = (const float*)d_in[2];
    const float* att_src1 = (const float*)d_in[3];
    const float* att_dst1 = (const float*)d_in[4];
    const float* b1       = (const float*)d_in[5];
    const float* W2       = (const float*)d_in[6];
    const float* att_src2 = (const float*)d_in[7];
    const float* att_dst2 = (const float*)d_in[8];
    const float* b2       = (const float*)d_in[9];
    float* out = (float*)d_out;

    // --- workspace layout (all regions 16B aligned) ---
    unsigned short* csr16 = (unsigned short*)d_ws;           // NN*64*2 = 6.4 MB
    unsigned short* h1b   = csr16 + (size_t)NN * 64;         // 25.6 MB
    unsigned short* Wt_bf = h1b + (size_t)NN * FH;           // 64 KB
    int*    pcnt  = (int*)(Wt_bf + FH * FIN);                // NN*32 = 6.4 MB
    int*    soff  = pcnt + (size_t)NN * R_REP;               // 6.4 MB
    int*    cnt   = soff + (size_t)NN * R_REP;               // 200 KB
    float*  a_s1  = (float*)(cnt + NN);                      // 800 KB
    float*  a_d1  = a_s1 + (size_t)NN * 4;                   // 800 KB
    float2* ndp   = (float2*)(a_d1 + (size_t)NN * 4);        // 2*NN*8 = 800 KB

    k_count<<<CNT_WGS + PREP_WGS, 1024, 0, stream>>>(ei, W1, Wt_bf, pcnt);
    k_gx<<<OFF_NB + GEMM_NB, 256, 0, stream>>>(x, Wt_bf, att_src1, att_dst1,
                                               pcnt, soff, cnt, csr16,
                                               h1b, a_s1, a_d1);
    k_scat2<<<CNT_WGS, 1024, 0, stream>>>(ei, soff, csr16);
    k_agg1<<<AGG1_GRID, 256, 0, stream>>>(cnt, csr16, a_s1, a_d1, h1b,
                                          b1, W2, ndp);
    k_agg2<<<(NN + 15) / 16, 256, 0, stream>>>(cnt, csr16, ndp,
                                               att_src2, att_dst2, b2, out);
}

// Round 4
// 239.793 us; speedup vs baseline: 1.0712x; 1.0712x over previous
//
#include <hip/hip_runtime.h>

#define NN     50000
#define E_RAW  800000
#define ETOT   (E_RAW + NN)   /* 850000: edges + self loops */
#define FIN    128
#define FH     256            /* HEADS*HID */
#define NEG    0.2f
#define BCAP   64             /* bucket capacity; P(deg>64) ~ 1e-18 */
#define L2E    1.44269504f    /* log2(e) */

/* Counting-sort CSR build.  R9: global atomics cap ~11 ops/ns -> LDS
   histograms.  R14 lesson: scatter needs its own 1024-thr dispatch.
   R15: P_PART 16->8 halves redundant edge-stream scanning. */
#define P_PART 8
#define DPW    6250             /* dsts per partition, 25KB LDS */
#define R_REP  32
#define EPW    (E_RAW / R_REP)  /* 25000 edges per replica */
#define CNT_WGS (P_PART * R_REP) /* 256 */
#define PREP_WGS 8              /* W1 transpose: 8 x 4096 elems */
#define OFF_NB  ((NN + 255) / 256)   /* 196 offset blocks */
#define GEMM_NB ((NN + 63) / 64)     /* 782 gemm blocks */

typedef __attribute__((ext_vector_type(8))) short s16x8;
typedef __attribute__((ext_vector_type(4))) float f32x4;

static __device__ __forceinline__ float leaky(float v) { return fmaxf(v, NEG * v); }

// 2^x via v_exp_f32 (what __expf lowers to, minus the log2e mul)
static __device__ __forceinline__ float ex2(float x) {
    float r; asm("v_exp_f32 %0, %1" : "=v"(r) : "v"(x)); return r;
}

// RNE float->bf16
static __device__ __forceinline__ unsigned short f2bf(float f) {
    unsigned u = __float_as_uint(f);
    unsigned r = u + 0x7fffu + ((u >> 16) & 1u);
    return (unsigned short)(r >> 16);
}

// ---------------------------------------------------------------------------
// D1: count pass + W1 prep.
// ---------------------------------------------------------------------------
__global__ __launch_bounds__(1024) void k_count(const int* __restrict__ ei,
                                                const float* __restrict__ W1,
                                                unsigned short* __restrict__ Wt_bf,
                                                int* __restrict__ pcnt)
{
    const int t = threadIdx.x;
    if (blockIdx.x >= CNT_WGS) {
        const int base = (blockIdx.x - CNT_WGS) * 4096;
        for (int i = t; i < 4096; i += 1024) {
            int idx = base + i;                 // < 32768
            int k = idx >> 8, col = idx & 255;
            Wt_bf[col * FIN + k] = f2bf(W1[k * FH + col]);
        }
        return;
    }
    __shared__ int lcnt[DPW];
    const int p  = blockIdx.x >> 5;
    const int r  = blockIdx.x & 31;
    const int lo = p * DPW;
    for (int i = t; i < DPW; i += 1024) lcnt[i] = 0;
    __syncthreads();
    const int ebase = r * EPW, eend = ebase + EPW;
    for (int e0 = ebase + t * 4; e0 < eend; e0 += 4096) {
        int4 dv4 = *(const int4*)&ei[E_RAW + e0];   // coalesced 16B
#pragma unroll
        for (int k = 0; k < 4; k++) {
            unsigned rel = (unsigned)((&dv4.x)[k] - lo);
            if (rel < DPW) atomicAdd(&lcnt[rel], 1);   // LDS, no return
        }
    }
    __syncthreads();
    for (int i = t; i < DPW; i += 1024)
        pcnt[r * NN + lo + i] = lcnt[i];
}

// ---------------------------------------------------------------------------
// D2: FUSED offsets + gemm.  a_s/a_d stored pre-scaled by log2(e) (leaky
// commutes with positive scale) so aggregation uses raw v_exp_f32.
// ---------------------------------------------------------------------------
__global__ __launch_bounds__(256) void k_gx(const float* __restrict__ x,
                                            const unsigned short* __restrict__ Wt_bf,
                                            const float* __restrict__ att_src,
                                            const float* __restrict__ att_dst,
                                            const int* __restrict__ pcnt,
                                            int* __restrict__ soff,
                                            int* __restrict__ cnt,
                                            unsigned short* __restrict__ csr16,
                                            unsigned short* __restrict__ h1b,
                                            float* __restrict__ a_s,
                                            float* __restrict__ a_d)
{
    const int t = threadIdx.x;
    if (blockIdx.x < OFF_NB) {
        int d = blockIdx.x * 256 + t;
        if (d >= NN) return;
        int run = 1;                     // slot 0 = self loop
#pragma unroll
        for (int r = 0; r < R_REP; r++) {
            soff[r * NN + d] = run;
            run += pcnt[r * NN + d];
        }
        cnt[d] = run;                    // clamped at use
        csr16[(size_t)d << 6] = (unsigned short)d;   // self-loop src
        return;
    }

    // ---------------- gemm path ----------------
    __shared__ unsigned short Sbuf[64 * 256];
    const int w    = t >> 6;
    const int lane = t & 63;
    const int li   = lane & 15;
    const int q8   = (lane >> 4) * 8;
    const int quad = lane >> 4;
    const int n0   = (blockIdx.x - OFF_NB) * 64;

    {
        const int node_l = t >> 2;
        const int k0 = (t & 3) * 32;
        int nn = n0 + node_l; if (nn >= NN) nn = NN - 1;
        const float* xp = &x[(size_t)nn * FIN + k0];
        unsigned short* xd = &Sbuf[node_l * 136 + k0];
#pragma unroll
        for (int i = 0; i < 8; i++) {
            float4 v = *(const float4*)&xp[i * 4];
            xd[i * 4 + 0] = f2bf(v.x);
            xd[i * 4 + 1] = f2bf(v.y);
            xd[i * 4 + 2] = f2bf(v.z);
            xd[i * 4 + 3] = f2bf(v.w);
        }
    }
    __syncthreads();

    f32x4 acc[4][4];
#pragma unroll
    for (int i = 0; i < 4; i++)
#pragma unroll
        for (int j = 0; j < 4; j++) acc[i][j] = (f32x4){0.f, 0.f, 0.f, 0.f};

#pragma unroll
    for (int kki = 0; kki < 4; kki++) {
        const int kk = kki * 32;
        s16x8 af[4], bf[4];
#pragma unroll
        for (int n16 = 0; n16 < 4; n16++) {
            int col = w * 64 + n16 * 16 + li;
            bf[n16] = *(const s16x8*)&Wt_bf[col * FIN + kk + q8];
        }
#pragma unroll
        for (int m16 = 0; m16 < 4; m16++)
            af[m16] = *(const s16x8*)&Sbuf[(m16 * 16 + li) * 136 + kk + q8];
#pragma unroll
        for (int m16 = 0; m16 < 4; m16++)
#pragma unroll
            for (int n16 = 0; n16 < 4; n16++)
                acc[m16][n16] = __builtin_amdgcn_mfma_f32_16x16x32_bf16(
                    af[m16], bf[n16], acc[m16][n16], 0, 0, 0);
    }

    // epilogue A: per-head attention logits (stored pre-scaled by log2 e)
    {
        float as_c[4], ad_c[4];
#pragma unroll
        for (int n16 = 0; n16 < 4; n16++) {
            int col = w * 64 + n16 * 16 + li;
            as_c[n16] = att_src[col];
            ad_c[n16] = att_dst[col];
        }
#pragma unroll
        for (int m16 = 0; m16 < 4; m16++) {
            float ps[4], pd[4];
#pragma unroll
            for (int reg = 0; reg < 4; reg++) {
                float s = 0.f, d = 0.f;
#pragma unroll
                for (int n16 = 0; n16 < 4; n16++) {
                    s += acc[m16][n16][reg] * as_c[n16];
                    d += acc[m16][n16][reg] * ad_c[n16];
                }
                ps[reg] = s; pd[reg] = d;
            }
#pragma unroll
            for (int off = 1; off < 16; off <<= 1) {
#pragma unroll
                for (int reg = 0; reg < 4; reg++) {
                    ps[reg] += __shfl_xor(ps[reg], off);
                    pd[reg] += __shfl_xor(pd[reg], off);
                }
            }
            if (li == 0) {
#pragma unroll
                for (int reg = 0; reg < 4; reg++) {
                    int node = n0 + m16 * 16 + quad * 4 + reg;
                    if (node < NN) {
                        a_s[node * 4 + w] = ps[reg] * L2E;
                        a_d[node * 4 + w] = pd[reg] * L2E;
                    }
                }
            }
        }
    }

    // epilogue B: bf16 store via LDS round-trip
    __syncthreads();
#pragma unroll
    for (int m16 = 0; m16 < 4; m16++)
#pragma unroll
        for (int n16 = 0; n16 < 4; n16++)
#pragma unroll
            for (int reg = 0; reg < 4; reg++)
                Sbuf[(m16 * 16 + quad * 4 + reg) * FH + w * 64 + n16 * 16 + li] =
                    f2bf(acc[m16][n16][reg]);
    __syncthreads();
    {
        const int node_l = t >> 2;
        const int c0 = (t & 3) * 64;
        int node = n0 + node_l;
        if (node < NN) {
#pragma unroll
            for (int i = 0; i < 8; i++)
                *(uint4*)&h1b[(size_t)node * FH + c0 + i * 8] =
                    *(const uint4*)&Sbuf[node_l * FH + c0 + i * 8];
        }
    }
}

// ---------------------------------------------------------------------------
// D3: scatter into contiguous buckets (uint16 payload: src < 2^16).
// ---------------------------------------------------------------------------
__global__ __launch_bounds__(1024) void k_scat2(const int* __restrict__ ei,
                                                const int* __restrict__ soff,
                                                unsigned short* __restrict__ csr16)
{
    __shared__ int cur[DPW];
    const int t  = threadIdx.x;
    const int p  = blockIdx.x >> 5;
    const int r  = blockIdx.x & 31;
    const int lo = p * DPW;
    for (int i = t; i < DPW; i += 1024)
        cur[i] = soff[r * NN + lo + i];
    __syncthreads();
    const int ebase = r * EPW, eend = ebase + EPW;
    for (int e0 = ebase + t * 4; e0 < eend; e0 += 4096) {
        int4 sv4 = *(const int4*)&ei[e0];           // coalesced 16B (src)
        int4 dv4 = *(const int4*)&ei[E_RAW + e0];   // coalesced 16B (dst)
#pragma unroll
        for (int k = 0; k < 4; k++) {
            int d = (&dv4.x)[k];
            unsigned rel = (unsigned)(d - lo);
            if (rel < DPW) {
                int pos = atomicAdd(&cur[rel], 1);  // LDS ds_add_rtn
                if (pos < BCAP)
                    csr16[((size_t)d << 6) + pos] = (unsigned short)(&sv4.x)[k];
            }
        }
    }
}

// ---------------------------------------------------------------------------
// D4: layer-1 aggregation, v5 = v1 REVERT (R19).  Evidence R16-R18: v1's
// structure (one wave per dst, lane owns 4 ch, ONE 512B dwordx2 row load per
// edge per wave, plain VGPR addressing, 50k waves oversubscribed) ran 3.09
// TB/s; every restructure (subgroup splits, scalar chains, persistent grid,
// channel halves) lost rate.  ~3.1 TB/s = fabric ceiling for this random
// 512B gather.  Kept orthogonal trims only:
//   - csr16 (u16): halves bucket-list fetch,
//   - v_exp_f32 with log2e pre-folded logits (one less VALU op/edge),
//   - unroll 4 -> 8: 2x rows in flight/wave (takes any latency margin).
// FUSED epilogue: /z, +b1, ELU, W2 projection, layer-2 logits -> nd4
// (z/w pre-scaled by log2 e for k_agg2's raw exp2).
// ---------------------------------------------------------------------------
__global__ __launch_bounds__(256) void k_agg1(const int* __restrict__ cnt,
                                              const unsigned short* __restrict__ csr16,
                                              const float* __restrict__ a_s1,
                                              const float* __restrict__ a_d1,
                                              const unsigned short* __restrict__ h1b,
                                              const float* __restrict__ b1,
                                              const float* __restrict__ W2,
                                              const float* __restrict__ att_src2,
                                              const float* __restrict__ att_dst2,
                                              float4* __restrict__ nd4)
{
    const int lane = threadIdx.x & 63;
    const int n = blockIdx.x * 4 + (threadIdx.x >> 6);
    if (n >= NN) return;
    int m = cnt[n]; if (m > BCAP) m = BCAP;
    const int h = lane >> 4;
    const float ad_h = a_d1[n * 4 + h];
    float acc0 = 0.f, acc1 = 0.f, acc2 = 0.f, acc3 = 0.f, z = 0.f;
    const unsigned short* sp = &csr16[(size_t)n << 6];
#pragma unroll 8
    for (int j = 0; j < m; j++) {
        int s = sp[j];                           // wave-uniform 2B
        float as_h = a_s1[s * 4 + h];
        float ex = ex2(leaky(as_h + ad_h));      // logits pre-scaled by log2 e
        unsigned long long wv =
            *(const unsigned long long*)(h1b + (size_t)s * FH + lane * 4);
        unsigned lo = (unsigned)wv, hi = (unsigned)(wv >> 32);
        acc0 += __uint_as_float(lo << 16) * ex;
        acc1 += __uint_as_float(lo & 0xffff0000u) * ex;
        acc2 += __uint_as_float(hi << 16) * ex;
        acc3 += __uint_as_float(hi & 0xffff0000u) * ex;
        z += ex;
    }
    const int c0 = lane * 4;
    float4 bb = *(const float4*)&b1[c0];
    const float rz = 1.0f / z;
    float v0 = acc0 * rz + bb.x;
    float v1 = acc1 * rz + bb.y;
    float v2 = acc2 * rz + bb.z;
    float v3 = acc3 * rz + bb.w;
    v0 = v0 > 0.f ? v0 : __expf(v0) - 1.f;   // ELU
    v1 = v1 > 0.f ? v1 : __expf(v1) - 1.f;
    v2 = v2 > 0.f ? v2 : __expf(v2) - 1.f;
    v3 = v3 > 0.f ? v3 : __expf(v3) - 1.f;
    float4 w2a = *(const float4*)&W2[c0 * 2];
    float4 w2b = *(const float4*)&W2[c0 * 2 + 4];
    float s0 = v0 * w2a.x + v1 * w2a.z + v2 * w2b.x + v3 * w2b.z;
    float s1 = v0 * w2a.y + v1 * w2a.w + v2 * w2b.y + v3 * w2b.w;
#pragma unroll
    for (int off = 32; off; off >>= 1) {
        s0 += __shfl_xor(s0, off);
        s1 += __shfl_xor(s1, off);
    }
    if (lane == 0) {
        float4 nd;
        nd.x = s0; nd.y = s1;
        nd.z = (s0 * att_src2[0] + s1 * att_src2[1]) * L2E;
        nd.w = (s0 * att_dst2[0] + s1 * att_dst2[1]) * L2E;
        nd4[n] = nd;
    }
}

// ---------------------------------------------------------------------------
// D5: layer-2 aggregation, 16 lanes per dst, contiguous u16 bucket; nd4.z/.w
// pre-scaled by log2 e -> raw exp2.  Writes d_out.
// ---------------------------------------------------------------------------
__global__ __launch_bounds__(256) void k_agg2(const int* __restrict__ cnt,
                                              const unsigned short* __restrict__ csr16,
                                              const float4* __restrict__ nd4,
                                              const float* __restrict__ b2,
                                              float* __restrict__ out)
{
    const int l = threadIdx.x & 15;
    const int n = blockIdx.x * 16 + (threadIdx.x >> 4);
    if (n >= NN) return;
    int m = cnt[n]; if (m > BCAP) m = BCAP;
    const unsigned short* sp = &csr16[(size_t)n << 6];
    const float ad = nd4[n].w;
    float z = 0.f, a0 = 0.f, a1 = 0.f;
    for (int j = l; j < m; j += 16) {
        int s = sp[j];
        float4 f = nd4[s];
        float ex = ex2(leaky(f.z + ad));
        z  += ex;
        a0 += f.x * ex;
        a1 += f.y * ex;
    }
#pragma unroll
    for (int off = 8; off; off >>= 1) {
        z  += __shfl_xor(z, off);
        a0 += __shfl_xor(a0, off);
        a1 += __shfl_xor(a1, off);
    }
    if (l == 0) {
        out[n * 2 + 0] = a0 / z + b2[0];
        out[n * 2 + 1] = a1 / z + b2[1];
    }
}

extern "C" void kernel_launch(void* const* d_in, const int* in_sizes, int n_in,
                              void* d_out, int out_size, void* d_ws, size_t ws_size,
                              hipStream_t stream)
{
    const float* x        = (const float*)d_in[0];
    const int*   ei       = (const int*)d_in[1];
    const float* W1       = (const float*)d_in[2];
    const float* att_src1 = (const float*)d_in[3];
    const float* att_dst1 = (const float*)d_in[4];
    const float* b1       = (const float*)d_in[5];
    const float* W2       = (const float*)d_in[6];
    const float* att_src2 = (const float*)d_in[7];
    const float* att_dst2 = (const float*)d_in[8];
    const float* b2       = (const float*)d_in[9];
    float* out = (float*)d_out;

    // --- workspace layout (all regions 16B aligned) ---
    unsigned short* csr16 = (unsigned short*)d_ws;           // NN*64*2 = 6.4 MB
    unsigned short* h1b   = csr16 + (size_t)NN * 64;         // 25.6 MB
    unsigned short* Wt_bf = h1b + (size_t)NN * FH;           // 64 KB
    int*    pcnt  = (int*)(Wt_bf + FH * FIN);                // NN*32 = 6.4 MB
    int*    soff  = pcnt + (size_t)NN * R_REP;               // 6.4 MB
    int*    cnt   = soff + (size_t)NN * R_REP;               // 200 KB
    float*  a_s1  = (float*)(cnt + NN);                      // 800 KB
    float*  a_d1  = a_s1 + (size_t)NN * 4;                   // 800 KB
    float4* nd4   = (float4*)(a_d1 + (size_t)NN * 4);        // 800 KB

    k_count<<<CNT_WGS + PREP_WGS, 1024, 0, stream>>>(ei, W1, Wt_bf, pcnt);
    k_gx<<<OFF_NB + GEMM_NB, 256, 0, stream>>>(x, Wt_bf, att_src1, att_dst1,
                                               pcnt, soff, cnt, csr16,
                                               h1b, a_s1, a_d1);
    k_scat2<<<CNT_WGS, 1024, 0, stream>>>(ei, soff, csr16);
    k_agg1<<<(NN + 3) / 4, 256, 0, stream>>>(cnt, csr16, a_s1, a_d1, h1b,
                                             b1, W2, att_src2, att_dst2, nd4);
    k_agg2<<<(NN + 15) / 16, 256, 0, stream>>>(cnt, csr16, nd4, b2, out);
}

// Round 5
// 201.665 us; speedup vs baseline: 1.2737x; 1.1891x over previous
//
#include <hip/hip_runtime.h>

#define NN     50000
#define E_RAW  800000
#define ETOT   (E_RAW + NN)   /* 850000: edges + self loops */
#define FIN    128
#define FH     256            /* HEADS*HID */
#define NEG    0.2f
#define BCAP   64             /* bucket capacity; P(deg>64) ~ 1e-18 */

/* Counting-sort CSR build.  R9: global atomics cap ~11 ops/ns -> LDS
   histograms.  R14 lesson: scatter needs its own 1024-thr dispatch.
   R15: P_PART 16->8 halves redundant edge-stream scanning.
   R19 lesson: k_agg1 codegen is fragile -- inline asm + unroll 8 dropped
   VGPR 24->16 (no overlapped row loads) and cost 50% of rate.  This round:
   EXACT v1 agg1 body; only metadata widths changed (u16). */
#define P_PART 8
#define DPW    6250             /* dsts per partition, 25KB LDS */
#define R_REP  32
#define EPW    (E_RAW / R_REP)  /* 25000 edges per replica */
#define CNT_WGS (P_PART * R_REP) /* 256 */
#define PREP_WGS 8              /* W1 transpose: 8 x 4096 elems */
#define OFF_NB  ((NN + 255) / 256)   /* 196 offset blocks */
#define GEMM_NB ((NN + 63) / 64)     /* 782 gemm blocks */

typedef __attribute__((ext_vector_type(8))) short s16x8;
typedef __attribute__((ext_vector_type(4))) float f32x4;

static __device__ __forceinline__ float leaky(float v) { return v > 0.f ? v : NEG * v; }

// RNE float->bf16
static __device__ __forceinline__ unsigned short f2bf(float f) {
    unsigned u = __float_as_uint(f);
    unsigned r = u + 0x7fffu + ((u >> 16) & 1u);
    return (unsigned short)(r >> 16);
}

// ---------------------------------------------------------------------------
// D1: count pass + W1 prep.
// blocks [0,256): WG(p=b>>5, r=b&31) histograms dst stream slice r into LDS
//   (non-returning ds_add), writes pcnt16[r*NN + d] coalesced (u16: counts
//   per replica-slice are tiny).
// blocks [256,264): W1 fp32 [k][col] -> bf16 Wt_bf[col][k] (strided).
// ---------------------------------------------------------------------------
__global__ __launch_bounds__(1024) void k_count(const int* __restrict__ ei,
                                                const float* __restrict__ W1,
                                                unsigned short* __restrict__ Wt_bf,
                                                unsigned short* __restrict__ pcnt16)
{
    const int t = threadIdx.x;
    if (blockIdx.x >= CNT_WGS) {
        const int base = (blockIdx.x - CNT_WGS) * 4096;
        for (int i = t; i < 4096; i += 1024) {
            int idx = base + i;                 // < 32768
            int k = idx >> 8, col = idx & 255;
            Wt_bf[col * FIN + k] = f2bf(W1[k * FH + col]);
        }
        return;
    }
    __shared__ int lcnt[DPW];
    const int p  = blockIdx.x >> 5;
    const int r  = blockIdx.x & 31;
    const int lo = p * DPW;
    for (int i = t; i < DPW; i += 1024) lcnt[i] = 0;
    __syncthreads();
    const int ebase = r * EPW, eend = ebase + EPW;
    for (int e0 = ebase + t * 4; e0 < eend; e0 += 4096) {
        int4 dv4 = *(const int4*)&ei[E_RAW + e0];   // coalesced 16B
#pragma unroll
        for (int k = 0; k < 4; k++) {
            unsigned rel = (unsigned)((&dv4.x)[k] - lo);
            if (rel < DPW) atomicAdd(&lcnt[rel], 1);   // LDS, no return
        }
    }
    __syncthreads();
    for (int i = t; i < DPW; i += 1024)
        pcnt16[r * NN + lo + i] = (unsigned short)lcnt[i];
}

// ---------------------------------------------------------------------------
// D2: FUSED offsets + gemm.
// blocks [0,196): per-dst prefix over 32 partial counts -> soff16[r*NN+d];
//   slot 0 reserved for self-loop (csr16[d*64]=d); cnt[d]=1+sum.
// blocks [196,978): h1 = x@W1 via MFMA bf16.
// ---------------------------------------------------------------------------
__global__ __launch_bounds__(256) void k_gx(const float* __restrict__ x,
                                            const unsigned short* __restrict__ Wt_bf,
                                            const float* __restrict__ att_src,
                                            const float* __restrict__ att_dst,
                                            const unsigned short* __restrict__ pcnt16,
                                            unsigned short* __restrict__ soff16,
                                            int* __restrict__ cnt,
                                            unsigned short* __restrict__ csr16,
                                            unsigned short* __restrict__ h1b,
                                            float* __restrict__ a_s,
                                            float* __restrict__ a_d)
{
    const int t = threadIdx.x;
    if (blockIdx.x < OFF_NB) {
        int d = blockIdx.x * 256 + t;
        if (d >= NN) return;
        int run = 1;                     // slot 0 = self loop
#pragma unroll
        for (int r = 0; r < R_REP; r++) {
            soff16[r * NN + d] = (unsigned short)run;
            run += pcnt16[r * NN + d];
        }
        cnt[d] = run;                    // clamped at use
        csr16[(size_t)d << 6] = (unsigned short)d;   // self-loop src
        return;
    }

    // ---------------- gemm path ----------------
    __shared__ unsigned short Sbuf[64 * 256];
    const int w    = t >> 6;
    const int lane = t & 63;
    const int li   = lane & 15;
    const int q8   = (lane >> 4) * 8;
    const int quad = lane >> 4;
    const int n0   = (blockIdx.x - OFF_NB) * 64;

    {
        const int node_l = t >> 2;
        const int k0 = (t & 3) * 32;
        int nn = n0 + node_l; if (nn >= NN) nn = NN - 1;
        const float* xp = &x[(size_t)nn * FIN + k0];
        unsigned short* xd = &Sbuf[node_l * 136 + k0];
#pragma unroll
        for (int i = 0; i < 8; i++) {
            float4 v = *(const float4*)&xp[i * 4];
            xd[i * 4 + 0] = f2bf(v.x);
            xd[i * 4 + 1] = f2bf(v.y);
            xd[i * 4 + 2] = f2bf(v.z);
            xd[i * 4 + 3] = f2bf(v.w);
        }
    }
    __syncthreads();

    f32x4 acc[4][4];
#pragma unroll
    for (int i = 0; i < 4; i++)
#pragma unroll
        for (int j = 0; j < 4; j++) acc[i][j] = (f32x4){0.f, 0.f, 0.f, 0.f};

#pragma unroll
    for (int kki = 0; kki < 4; kki++) {
        const int kk = kki * 32;
        s16x8 af[4], bf[4];
#pragma unroll
        for (int n16 = 0; n16 < 4; n16++) {
            int col = w * 64 + n16 * 16 + li;
            bf[n16] = *(const s16x8*)&Wt_bf[col * FIN + kk + q8];
        }
#pragma unroll
        for (int m16 = 0; m16 < 4; m16++)
            af[m16] = *(const s16x8*)&Sbuf[(m16 * 16 + li) * 136 + kk + q8];
#pragma unroll
        for (int m16 = 0; m16 < 4; m16++)
#pragma unroll
            for (int n16 = 0; n16 < 4; n16++)
                acc[m16][n16] = __builtin_amdgcn_mfma_f32_16x16x32_bf16(
                    af[m16], bf[n16], acc[m16][n16], 0, 0, 0);
    }

    // epilogue A: per-head attention logits
    {
        float as_c[4], ad_c[4];
#pragma unroll
        for (int n16 = 0; n16 < 4; n16++) {
            int col = w * 64 + n16 * 16 + li;
            as_c[n16] = att_src[col];
            ad_c[n16] = att_dst[col];
        }
#pragma unroll
        for (int m16 = 0; m16 < 4; m16++) {
            float ps[4], pd[4];
#pragma unroll
            for (int reg = 0; reg < 4; reg++) {
                float s = 0.f, d = 0.f;
#pragma unroll
                for (int n16 = 0; n16 < 4; n16++) {
                    s += acc[m16][n16][reg] * as_c[n16];
                    d += acc[m16][n16][reg] * ad_c[n16];
                }
                ps[reg] = s; pd[reg] = d;
            }
#pragma unroll
            for (int off = 1; off < 16; off <<= 1) {
#pragma unroll
                for (int reg = 0; reg < 4; reg++) {
                    ps[reg] += __shfl_xor(ps[reg], off);
                    pd[reg] += __shfl_xor(pd[reg], off);
                }
            }
            if (li == 0) {
#pragma unroll
                for (int reg = 0; reg < 4; reg++) {
                    int node = n0 + m16 * 16 + quad * 4 + reg;
                    if (node < NN) {
                        a_s[node * 4 + w] = ps[reg];
                        a_d[node * 4 + w] = pd[reg];
                    }
                }
            }
        }
    }

    // epilogue B: bf16 store via LDS round-trip
    __syncthreads();
#pragma unroll
    for (int m16 = 0; m16 < 4; m16++)
#pragma unroll
        for (int n16 = 0; n16 < 4; n16++)
#pragma unroll
            for (int reg = 0; reg < 4; reg++)
                Sbuf[(m16 * 16 + quad * 4 + reg) * FH + w * 64 + n16 * 16 + li] =
                    f2bf(acc[m16][n16][reg]);
    __syncthreads();
    {
        const int node_l = t >> 2;
        const int c0 = (t & 3) * 64;
        int node = n0 + node_l;
        if (node < NN) {
#pragma unroll
            for (int i = 0; i < 8; i++)
                *(uint4*)&h1b[(size_t)node * FH + c0 + i * 8] =
                    *(const uint4*)&Sbuf[node_l * FH + c0 + i * 8];
        }
    }
}

// ---------------------------------------------------------------------------
// D3: scatter into contiguous buckets (u16 payload: src < 2^16; halves the
// random write-allocate footprint to 2 lines/bucket).  1024-thread WGs
// (R14 lesson: do NOT shrink).
// ---------------------------------------------------------------------------
__global__ __launch_bounds__(1024) void k_scat2(const int* __restrict__ ei,
                                                const unsigned short* __restrict__ soff16,
                                                unsigned short* __restrict__ csr16)
{
    __shared__ int cur[DPW];
    const int t  = threadIdx.x;
    const int p  = blockIdx.x >> 5;
    const int r  = blockIdx.x & 31;
    const int lo = p * DPW;
    for (int i = t; i < DPW; i += 1024)
        cur[i] = soff16[r * NN + lo + i];
    __syncthreads();
    const int ebase = r * EPW, eend = ebase + EPW;
    for (int e0 = ebase + t * 4; e0 < eend; e0 += 4096) {
        int4 sv4 = *(const int4*)&ei[e0];           // coalesced 16B (src)
        int4 dv4 = *(const int4*)&ei[E_RAW + e0];   // coalesced 16B (dst)
#pragma unroll
        for (int k = 0; k < 4; k++) {
            int d = (&dv4.x)[k];
            unsigned rel = (unsigned)(d - lo);
            if (rel < DPW) {
                int pos = atomicAdd(&cur[rel], 1);  // LDS ds_add_rtn
                if (pos < BCAP)
                    csr16[((size_t)d << 6) + pos] = (unsigned short)(&sv4.x)[k];
            }
        }
    }
}

// ---------------------------------------------------------------------------
// D4: layer-1 aggregation -- EXACT R0/v1 body (measured 69 us, VGPR 24,
// 3.09 TB/s fetch: the empirical optimum across v1-v5; see R16-R19 ladder).
// ONE wave per dst; lane l owns channels 4l..4l+3; 8B h1b gather + per-lane
// a_s1 + in-loop __expf; unroll 4.  Single controlled change vs v1: sp
// reads u16 (wave-uniform 2B).  If this round regresses agg1 >80us, the u16
// read is guilty -> revert to int32 csr next round.
// FUSED: /z, +b1, ELU, W2 projection, layer-2 logits -> nd4.
// ---------------------------------------------------------------------------
__global__ __launch_bounds__(256) void k_agg1(const int* __restrict__ cnt,
                                              const unsigned short* __restrict__ csr16,
                                              const float* __restrict__ a_s1,
                                              const float* __restrict__ a_d1,
                                              const unsigned short* __restrict__ h1b,
                                              const float* __restrict__ b1,
                                              const float* __restrict__ W2,
                                              const float* __restrict__ att_src2,
                                              const float* __restrict__ att_dst2,
                                              float4* __restrict__ nd4)
{
    const int lane = threadIdx.x & 63;
    const int n = blockIdx.x * 4 + (threadIdx.x >> 6);
    if (n >= NN) return;
    int m = cnt[n]; if (m > BCAP) m = BCAP;
    const int h = lane >> 4;
    const float ad_h = a_d1[n * 4 + h];
    float acc0 = 0.f, acc1 = 0.f, acc2 = 0.f, acc3 = 0.f, z = 0.f;
    const unsigned short* sp = &csr16[(size_t)n << 6];
#pragma unroll 4
    for (int j = 0; j < m; j++) {
        int s = sp[j];                           // wave-uniform 2B
        float as_h = a_s1[s * 4 + h];
        float ex = __expf(leaky(as_h + ad_h));
        unsigned long long wv =
            *(const unsigned long long*)(h1b + (size_t)s * FH + lane * 4);
        unsigned lo = (unsigned)wv, hi = (unsigned)(wv >> 32);
        acc0 += __uint_as_float(lo << 16) * ex;
        acc1 += __uint_as_float(lo & 0xffff0000u) * ex;
        acc2 += __uint_as_float(hi << 16) * ex;
        acc3 += __uint_as_float(hi & 0xffff0000u) * ex;
        z += ex;
    }
    const int c0 = lane * 4;
    float4 bb = *(const float4*)&b1[c0];
    float v0 = acc0 / z + bb.x;
    float v1 = acc1 / z + bb.y;
    float v2 = acc2 / z + bb.z;
    float v3 = acc3 / z + bb.w;
    v0 = v0 > 0.f ? v0 : __expf(v0) - 1.f;   // ELU
    v1 = v1 > 0.f ? v1 : __expf(v1) - 1.f;
    v2 = v2 > 0.f ? v2 : __expf(v2) - 1.f;
    v3 = v3 > 0.f ? v3 : __expf(v3) - 1.f;
    float4 w2a = *(const float4*)&W2[c0 * 2];
    float4 w2b = *(const float4*)&W2[c0 * 2 + 4];
    float s0 = v0 * w2a.x + v1 * w2a.z + v2 * w2b.x + v3 * w2b.z;
    float s1 = v0 * w2a.y + v1 * w2a.w + v2 * w2b.y + v3 * w2b.w;
#pragma unroll
    for (int off = 32; off; off >>= 1) {
        s0 += __shfl_xor(s0, off);
        s1 += __shfl_xor(s1, off);
    }
    if (lane == 0) {
        float4 nd;
        nd.x = s0; nd.y = s1;
        nd.z = s0 * att_src2[0] + s1 * att_src2[1];
        nd.w = s0 * att_dst2[0] + s1 * att_dst2[1];
        nd4[n] = nd;
    }
}

// ---------------------------------------------------------------------------
// D5: layer-2 aggregation, 16 lanes per dst, contiguous u16 bucket; writes
// d_out.  EXACT R0 body except u16 sp.
// ---------------------------------------------------------------------------
__global__ __launch_bounds__(256) void k_agg2(const int* __restrict__ cnt,
                                              const unsigned short* __restrict__ csr16,
                                              const float4* __restrict__ nd4,
                                              const float* __restrict__ b2,
                                              float* __restrict__ out)
{
    const int l = threadIdx.x & 15;
    const int n = blockIdx.x * 16 + (threadIdx.x >> 4);
    if (n >= NN) return;
    int m = cnt[n]; if (m > BCAP) m = BCAP;
    const unsigned short* sp = &csr16[(size_t)n << 6];
    const float ad = nd4[n].w;
    float z = 0.f, a0 = 0.f, a1 = 0.f;
    for (int j = l; j < m; j += 16) {
        int s = sp[j];
        float4 f = nd4[s];
        float ex = __expf(leaky(f.z + ad));
        z  += ex;
        a0 += f.x * ex;
        a1 += f.y * ex;
    }
#pragma unroll
    for (int off = 8; off; off >>= 1) {
        z  += __shfl_xor(z, off);
        a0 += __shfl_xor(a0, off);
        a1 += __shfl_xor(a1, off);
    }
    if (l == 0) {
        out[n * 2 + 0] = a0 / z + b2[0];
        out[n * 2 + 1] = a1 / z + b2[1];
    }
}

extern "C" void kernel_launch(void* const* d_in, const int* in_sizes, int n_in,
                              void* d_out, int out_size, void* d_ws, size_t ws_size,
                              hipStream_t stream)
{
    const float* x        = (const float*)d_in[0];
    const int*   ei       = (const int*)d_in[1];
    const float* W1       = (const float*)d_in[2];
    const float* att_src1 = (const float*)d_in[3];
    const float* att_dst1 = (const float*)d_in[4];
    const float* b1       = (const float*)d_in[5];
    const float* W2       = (const float*)d_in[6];
    const float* att_src2 = (const float*)d_in[7];
    const float* att_dst2 = (const float*)d_in[8];
    const float* b2       = (const float*)d_in[9];
    float* out = (float*)d_out;

    // --- workspace layout (all regions 16B aligned) ---
    unsigned short* csr16 = (unsigned short*)d_ws;           // NN*64*2 = 6.4 MB
    unsigned short* h1b   = csr16 + (size_t)NN * 64;         // 25.6 MB
    unsigned short* Wt_bf = h1b + (size_t)NN * FH;           // 64 KB
    unsigned short* pcnt16 = Wt_bf + FH * FIN;               // NN*32*2 = 3.2 MB
    unsigned short* soff16 = pcnt16 + (size_t)NN * R_REP;    // 3.2 MB
    int*    cnt   = (int*)(soff16 + (size_t)NN * R_REP);     // 200 KB
    float*  a_s1  = (float*)(cnt + NN);                      // 800 KB
    float*  a_d1  = a_s1 + (size_t)NN * 4;                   // 800 KB
    float4* nd4   = (float4*)(a_d1 + (size_t)NN * 4);        // 800 KB

    k_count<<<CNT_WGS + PREP_WGS, 1024, 0, stream>>>(ei, W1, Wt_bf, pcnt16);
    k_gx<<<OFF_NB + GEMM_NB, 256, 0, stream>>>(x, Wt_bf, att_src1, att_dst1,
                                               pcnt16, soff16, cnt, csr16,
                                               h1b, a_s1, a_d1);
    k_scat2<<<CNT_WGS, 1024, 0, stream>>>(ei, soff16, csr16);
    k_agg1<<<(NN + 3) / 4, 256, 0, stream>>>(cnt, csr16, a_s1, a_d1, h1b,
                                             b1, W2, att_src2, att_dst2, nd4);
    k_agg2<<<(NN + 15) / 16, 256, 0, stream>>>(cnt, csr16, nd4, b2, out);
}